// Round 9
// baseline (140.359 us; speedup 1.0000x reference)
//
#include <hip/hip_runtime.h>
#include <math.h>

// Problem constants
static constexpr int GRIDN = 30;
static constexpr int S    = 900;
static constexpr int D    = 512;
static constexpr int HQ   = 8;
static constexpr int HKV  = 2;
static constexpr int T    = 16;
static constexpr int NTOK = 1 + T*S + S;   // 15301
static constexpr int CUR0 = 1 + T*S;       // 14401

static constexpr int THROWS = 15360;       // padded KV rows
static constexpr int VTC    = 960;         // Vt columns
static constexpr int PBS    = 952;         // P LDS row stride (halves)
static constexpr int LSTR   = 72;          // proj LDS row stride (halves, 144B: 16B-aligned rows)

typedef _Float16 half8  __attribute__((ext_vector_type(8)));
typedef _Float16 half4  __attribute__((ext_vector_type(4)));
typedef __fp16   fp16x2 __attribute__((ext_vector_type(2)));
typedef float    floatx4 __attribute__((ext_vector_type(4)));

#define MFMA16(a,b,c) __builtin_amdgcn_mfma_f32_16x16x32_f16((a),(b),(c),0,0,0)

#if defined(__has_builtin)
#if __has_builtin(__builtin_amdgcn_fdot2)
#define HAVE_FDOT2 1
#endif
#endif

// Bijective XCD-chunk swizzle (m204): consecutive LOGICAL ids land on the
// same XCD (hardware round-robins blockIdx across 8 XCDs).
__device__ __forceinline__ int xcd_swizzle(int bx, int nwg) {
    const int q = nwg >> 3, r = nwg & 7;
    const int xcd = bx & 7, idx = bx >> 3;
    return (xcd < r ? xcd * (q + 1) : r * (q + 1) + (xcd - r) * q) + idx;
}

__device__ __forceinline__ half8 to_half8(float4 a, float4 b) {
    half8 h;
    h[0]=(_Float16)a.x; h[1]=(_Float16)a.y; h[2]=(_Float16)a.z; h[3]=(_Float16)a.w;
    h[4]=(_Float16)b.x; h[5]=(_Float16)b.y; h[6]=(_Float16)b.z; h[7]=(_Float16)b.w;
    return h;
}

// pack 4 fp32 -> 4 fp16 via v_cvt_pkrtz
__device__ __forceinline__ half4 cvt4(float4 a) {
    const fp16x2 p0 = __builtin_amdgcn_cvt_pkrtz(a.x, a.y);
    const fp16x2 p1 = __builtin_amdgcn_cvt_pkrtz(a.z, a.w);
    half4 h;
    h[0]=(_Float16)p0[0]; h[1]=(_Float16)p0[1];
    h[2]=(_Float16)p1[0]; h[3]=(_Float16)p1[1];
    return h;
}

// ---------------------------------------------------------------------------
// prep_w: weights fp32 -> fp16 only.
// ---------------------------------------------------------------------------
__global__ __launch_bounds__(256) void prep_w(
    const float* __restrict__ Wq, const float* __restrict__ Wk,
    const float* __restrict__ Wv, const float* __restrict__ Wo,
    _Float16* __restrict__ Wqh, _Float16* __restrict__ Whkv,
    _Float16* __restrict__ Woh)
{
    const size_t i8 = ((size_t)blockIdx.x * 256 + threadIdx.x) * 8;
    const float* src; _Float16* dst; size_t off;
    if (i8 < 262144)      { src = Wq; dst = Wqh;          off = i8; }
    else if (i8 < 327680) { src = Wk; dst = Whkv;         off = i8 - 262144; }
    else if (i8 < 393216) { src = Wv; dst = Whkv + 65536; off = i8 - 327680; }
    else                  { src = Wo; dst = Woh;          off = i8 - 393216; }
    const float4 f0 = *(const float4*)(src + off);
    const float4 f1 = *(const float4*)(src + off + 4);
    *(half8*)(dst + off) = to_half8(f0, f1);
}

// ---------------------------------------------------------------------------
// proj: LDS-staged double-buffered GEMM + fused RoPE + V transpose.
// BM=32 x BN=128 x BK=64, 4 waves (2x2). Logical ids (post-swizzle):
//   0..959:    KV (mtile = lg>>1, bc = lg&1: 0=K, 1=V)  -- pair shares A tile
//   960..1075: Q  (qb = lg-960: mtile = qb>>2, bc = qb&3) -- quad shares A tile
// XCD swizzle puts each sharing group on one XCD -> A re-reads hit L2.
// ---------------------------------------------------------------------------
__global__ __launch_bounds__(256) void proj(
    const float* __restrict__ init_e, const float* __restrict__ hist,
    const float* __restrict__ cur,
    const _Float16* __restrict__ Whkv, const _Float16* __restrict__ Wqh,
    _Float16* __restrict__ Kh, _Float16* __restrict__ Vh,
    _Float16* __restrict__ Vt, _Float16* __restrict__ Qh)
{
    __shared__ _Float16 Alds[2][32 * LSTR];    // 9.2 KB
    __shared__ _Float16 Blds[2][128 * LSTR];   // 36.9 KB

    const int tid  = threadIdx.x;
    const int w    = tid >> 6, lane = tid & 63;
    const int r    = lane & 15, kb = lane >> 4;
    const int ww   = w >> 1, wc = w & 1;       // wave row/col in 2x2 grid
    const int lg   = xcd_swizzle(blockIdx.x, 1076);
    const bool isQ = (lg >= 960);

    int l0, n0, bc;
    const _Float16* Wb;
    if (!isQ) { l0 = (lg >> 1) * 32;               bc = lg & 1;  n0 = bc * 128; Wb = Whkv; }
    else      { const int qb = lg - 960;
                l0 = CUR0 + (qb >> 2) * 32;        bc = qb & 3;  n0 = bc * 128; Wb = Wqh; }

    // ---- staging source pointers ----
    const float* arow[2];
    #pragma unroll
    for (int j = 0; j < 2; ++j) {
        int l = l0 + j * 16 + (tid >> 4);
        if (l >= NTOK) l = 0;
        const float* rp = (l == 0) ? init_e
                        : (l <= T*S ? hist + (size_t)(l - 1) * 512
                                    : cur  + (size_t)(l - CUR0) * 512);
        arow[j] = rp + (tid & 15) * 4;
    }
    const _Float16* brow[4];
    #pragma unroll
    for (int j = 0; j < 4; ++j)
        brow[j] = Wb + (size_t)(n0 + j * 32 + (tid >> 3)) * 512 + (tid & 7) * 8;

    float4 areg[2];
    half8  breg[4];

    floatx4 acc[4] = {};

    // prologue: chunk 0
    #pragma unroll
    for (int j = 0; j < 2; ++j) areg[j] = *(const float4*)arow[j];
    #pragma unroll
    for (int j = 0; j < 4; ++j) breg[j] = *(const half8*)brow[j];
    #pragma unroll
    for (int j = 0; j < 2; ++j)
        *(half4*)&Alds[0][(j*16 + (tid >> 4)) * LSTR + (tid & 15) * 4] = cvt4(areg[j]);
    #pragma unroll
    for (int j = 0; j < 4; ++j)
        *(half8*)&Blds[0][(j*32 + (tid >> 3)) * LSTR + (tid & 7) * 8]  = breg[j];
    __syncthreads();

    for (int c = 0; c < 8; ++c) {
        const int buf = c & 1;
        if (c < 7) {
            const int k0 = (c + 1) * 64;
            #pragma unroll
            for (int j = 0; j < 2; ++j) areg[j] = *(const float4*)(arow[j] + k0);
            #pragma unroll
            for (int j = 0; j < 4; ++j) breg[j] = *(const half8*)(brow[j] + k0);
        }
        // compute chunk c from LDS[buf]
        #pragma unroll
        for (int s = 0; s < 2; ++s) {
            const half8 a = *(const half8*)&Alds[buf][(ww*16 + r) * LSTR + s*32 + kb*8];
            #pragma unroll
            for (int nt = 0; nt < 4; ++nt) {
                const half8 b = *(const half8*)&Blds[buf][(wc*64 + nt*16 + r) * LSTR + s*32 + kb*8];
                acc[nt] = MFMA16(a, b, acc[nt]);
            }
        }
        if (c < 7) {
            __syncthreads();
            #pragma unroll
            for (int j = 0; j < 2; ++j)
                *(half4*)&Alds[buf ^ 1][(j*16 + (tid >> 4)) * LSTR + (tid & 15) * 4] = cvt4(areg[j]);
            #pragma unroll
            for (int j = 0; j < 4; ++j)
                *(half8*)&Blds[buf ^ 1][(j*32 + (tid >> 3)) * LSTR + (tid & 7) * 8]  = breg[j];
            __syncthreads();
        }
    }

    // ---- epilogue: RoPE + stores ----
    const float LN1E4 = 9.210340371976184f;
    float inv1[4], inv2[4]; int jj[4];
    #pragma unroll
    for (int nt = 0; nt < 4; ++nt) {
        const int cl = nt * 16 + r;          // dim within 64-wide head
        jj[nt] = cl >> 1;
        inv1[nt] = __expf(-(float)jj[nt]        * (LN1E4 / 32.f));
        inv2[nt] = __expf(-(float)(jj[nt] & 15) * (LN1E4 / 16.f));
    }

    if (!isQ) {
        if (bc == 0) {
            // ---- K with rope: col cc = wc*64 + nt*16 + r in [0,128) ----
            #pragma unroll
            for (int i = 0; i < 4; ++i) {
                const int l = l0 + ww*16 + kb*4 + i;
                float pos, cy, cx;
                if (l == 0) { pos = 0.f; cy = 0.f; cx = 0.f; }
                else if (l <= T*S) {
                    const int j2 = l - 1;
                    const int t_ = j2 / S;
                    const int cell = j2 - t_ * S;
                    pos = (float)t_;
                    cy = (float)(cell / GRIDN); cx = (float)(cell % GRIDN);
                } else {
                    const int cell = l - CUR0;
                    pos = (float)T;
                    cy = (float)(cell / GRIDN); cx = (float)(cell % GRIDN);
                }
                #pragma unroll
                for (int nt = 0; nt < 4; ++nt) {
                    const float own = acc[nt][i];
                    const float oth = __shfl_xor(own, 1);
                    const float c2 = (jj[nt] < 16) ? cy : cx;
                    const float theta = pos * inv1[nt] + c2 * inv2[nt];
                    float sn, cs; __sincosf(theta, &sn, &cs);
                    const int cc = wc*64 + nt*16 + r;
                    const float o = ((cc & 1) == 0) ? (own * cs - oth * sn)
                                                    : (oth * sn + own * cs);
                    if (l < NTOK) Kh[(size_t)l * 128 + cc] = (_Float16)o;
                }
            }
        } else {
            // ---- V (no rope): vd = wc*64 + nt*16 + r in [0,128) ----
            #pragma unroll
            for (int nt = 0; nt < 4; ++nt) {
                const int vd = wc*64 + nt*16 + r;
                #pragma unroll
                for (int i = 0; i < 4; ++i) {
                    const int l = l0 + ww*16 + kb*4 + i;
                    if (l >= NTOK) continue;
                    const _Float16 hv = (_Float16)acc[nt][i];
                    Vh[(size_t)l * 128 + vd] = hv;
                    const int cc = l - CUR0;
                    if (cc >= 0 && cc < S)
                        Vt[(size_t)vd * VTC + cc] = hv;   // vd == kvh*64 + d
                }
            }
        }
    } else {
        // ---- Q with rope + 0.125 scale: col C = bc*128 + wc*64 + nt*16 + r ----
        #pragma unroll
        for (int i = 0; i < 4; ++i) {
            const int l = l0 + ww*16 + kb*4 + i;
            const int s = l - CUR0;
            const int ssafe = (s < S) ? s : 0;
            const float cy = (float)(ssafe / GRIDN), cx = (float)(ssafe % GRIDN);
            #pragma unroll
            for (int nt = 0; nt < 4; ++nt) {
                const float own = acc[nt][i];
                const float oth = __shfl_xor(own, 1);
                const float c2 = (jj[nt] < 16) ? cy : cx;
                const float theta = 16.f * inv1[nt] + c2 * inv2[nt];
                float sn, cs; __sincosf(theta, &sn, &cs);
                const int C = bc*128 + wc*64 + nt*16 + r;
                const float o = ((C & 1) == 0) ? (own * cs - oth * sn)
                                               : (oth * sn + own * cs);
                if (s < S)
                    Qh[(size_t)s * 512 + C] = (_Float16)(o * 0.125f);
            }
        }
    }
}

// ---------------------------------------------------------------------------
// Attention: block = (16-query tile, head); 4 waves. Dense 900 keys via MFMA,
// 17 masked extras (init + same-cell history) via dot2 VALU.
// ---------------------------------------------------------------------------
__global__ __launch_bounds__(256) void attn_f16(
    const _Float16* __restrict__ Qh, const _Float16* __restrict__ Kh,
    const _Float16* __restrict__ Vt, const _Float16* __restrict__ Vh,
    _Float16* __restrict__ Oh)
{
    __shared__ _Float16 pb[16][PBS];
    __shared__ float ex[16][20];
    __shared__ float wpm[4][16], wps[4][16];
    __shared__ float rowm[16], rowinv[16];
    __shared__ float Oe[16][68];

    const int q0  = blockIdx.x * 16;
    const int h   = blockIdx.y;
    const int kvh = h >> 2;
    const int tid = threadIdx.x;
    const int w = tid >> 6, lane = tid & 63;
    const int r = lane & 15, g = lane >> 4;

    // ---- phase A: extras raw scores ----
    {
        const int er = tid & 15;
        const int s  = q0 + er;
        const int ss = (s < S) ? s : 0;
        const _Float16* qp = Qh + (size_t)(q0 + er) * 512 + h * 64;
        for (int e = tid >> 4; e < 17; e += 16) {
            const int l = (e == 0) ? 0 : (1 + (e - 1) * S + ss);
            const _Float16* kp = Kh + (size_t)l * 128 + kvh * 64;
            float acc = 0.f;
            #pragma unroll
            for (int d8 = 0; d8 < 8; ++d8) {
                const half8 qv = *(const half8*)(qp + d8 * 8);
                const half8 kv = *(const half8*)(kp + d8 * 8);
#ifdef HAVE_FDOT2
                #pragma unroll
                for (int p_ = 0; p_ < 4; ++p_) {
                    fp16x2 qq; qq[0] = (__fp16)qv[2*p_]; qq[1] = (__fp16)qv[2*p_+1];
                    fp16x2 kk; kk[0] = (__fp16)kv[2*p_]; kk[1] = (__fp16)kv[2*p_+1];
                    acc = __builtin_amdgcn_fdot2(qq, kk, acc, false);
                }
#else
                #pragma unroll
                for (int q_ = 0; q_ < 8; ++q_)
                    acc += (float)qv[q_] * (float)kv[q_];
#endif
            }
            ex[er][e] = acc;
        }
    }

    // ---- phase B: dense QK^T in registers ----
    half8 qa[2];
    #pragma unroll
    for (int ks = 0; ks < 2; ++ks)
        qa[ks] = *(const half8*)(Qh + (size_t)(q0 + r) * 512 + h * 64 + ks * 32 + g * 8);

    floatx4 qacc[15];
    #pragma unroll
    for (int t = 0; t < 15; ++t) {
        const int nt = w + 4 * t;
        floatx4 a = {0.f, 0.f, 0.f, 0.f};
        if (nt <= 56) {
            const _Float16* kp = Kh + (size_t)(CUR0 + nt * 16 + r) * 128 + kvh * 64 + g * 8;
            a = MFMA16(qa[0], *(const half8*)kp, a);
            a = MFMA16(qa[1], *(const half8*)(kp + 32), a);
        }
        qacc[t] = a;
    }

    float pm[4] = {-1e30f, -1e30f, -1e30f, -1e30f};
    #pragma unroll
    for (int t = 0; t < 15; ++t) {
        const int nt = w + 4 * t;
        const bool valid = (nt <= 56) && !((nt == 56) && (r >= 4));
        #pragma unroll
        for (int i = 0; i < 4; ++i)
            if (valid) pm[i] = fmaxf(pm[i], qacc[t][i]);
    }
    #pragma unroll
    for (int m = 1; m < 16; m <<= 1)
        #pragma unroll
        for (int i = 0; i < 4; ++i)
            pm[i] = fmaxf(pm[i], __shfl_xor(pm[i], m));
    if (r == 0)
        #pragma unroll
        for (int i = 0; i < 4; ++i) wpm[w][g * 4 + i] = pm[i];
    __syncthreads();

    if (tid < 16) {
        float m = fmaxf(fmaxf(wpm[0][tid], wpm[1][tid]), fmaxf(wpm[2][tid], wpm[3][tid]));
        #pragma unroll
        for (int e = 0; e < 17; ++e) m = fmaxf(m, ex[tid][e]);
        rowm[tid] = m;
    }
    __syncthreads();

    // ---- phase C: exp + row sums ----
    {
        const int er = tid & 15;
        for (int e = tid >> 4; e < 17; e += 16)
            ex[er][e] = __expf(ex[er][e] - rowm[er]);
    }
    pb[tid >> 4][912 + (tid & 15)] = (_Float16)0.f;

    float ps[4] = {0.f, 0.f, 0.f, 0.f};
    #pragma unroll
    for (int t = 0; t < 15; ++t) {
        const int nt = w + 4 * t;
        if (nt <= 56) {
            const int c = nt * 16 + r;
            const bool masked = (nt == 56) && (r >= 4);
            #pragma unroll
            for (int i = 0; i < 4; ++i) {
                const int row = g * 4 + i;
                const float e = masked ? 0.f : __expf(qacc[t][i] - rowm[row]);
                ps[i] += e;
                pb[row][c] = (_Float16)e;
            }
        }
    }
    #pragma unroll
    for (int m = 1; m < 16; m <<= 1)
        #pragma unroll
        for (int i = 0; i < 4; ++i) ps[i] += __shfl_xor(ps[i], m);
    if (r == 0)
        #pragma unroll
        for (int i = 0; i < 4; ++i) wps[w][g * 4 + i] = ps[i];
    __syncthreads();

    if (tid < 16) {
        float s_ = wps[0][tid] + wps[1][tid] + wps[2][tid] + wps[3][tid];
        #pragma unroll
        for (int e = 0; e < 17; ++e) s_ += ex[tid][e];
        rowinv[tid] = 1.f / s_;
    }
    __syncthreads();

    // ---- phase D: extras PV (fp16 V, fp32 accum) ----
    {
        const int er = tid & 15, gg = tid >> 4;
        const int s  = q0 + er;
        const int ss = (s < S) ? s : 0;
        float o0 = 0.f, o1 = 0.f, o2 = 0.f, o3 = 0.f;
        for (int e = 0; e < 17; ++e) {
            const int l = (e == 0) ? 0 : (1 + (e - 1) * S + ss);
            const float p = ex[er][e];
            const half4 v = *(const half4*)(Vh + (size_t)l * 128 + kvh * 64 + gg * 4);
            o0 = fmaf(p, (float)v[0], o0); o1 = fmaf(p, (float)v[1], o1);
            o2 = fmaf(p, (float)v[2], o2); o3 = fmaf(p, (float)v[3], o3);
        }
        *(float4*)&Oe[er][gg * 4] = make_float4(o0, o1, o2, o3);
    }

    // ---- phase E: dense PV via MFMA ----
    const int d0 = w * 16;
    floatx4 oa = {0.f, 0.f, 0.f, 0.f};
    const _Float16* vrow = Vt + ((size_t)kvh * 64 + d0 + r) * VTC + g * 8;
    #pragma unroll
    for (int ks = 0; ks < 29; ++ks) {
        const half8 pf = *(const half8*)(&pb[r][ks * 32 + g * 8]);
        const half8 vf = *(const half8*)(vrow + ks * 32);
        oa = MFMA16(pf, vf, oa);
    }
    __syncthreads();

    #pragma unroll
    for (int i = 0; i < 4; ++i) {
        const int row = g * 4 + i;
        const int s = q0 + row;
        if (s < S) {
            const float o = (oa[i] + Oe[row][d0 + r]) * rowinv[row];
            Oh[(size_t)s * 512 + h * 64 + d0 + r] = (_Float16)o;
        }
    }
}

// ---------------------------------------------------------------------------
// Out(fp32)[M][512] = A(fp16, padded rows)[.][512] @ Wh^T.
// 1-D grid of 58 blocks; XCD swizzle pairs (l0, n0=0/256) on the same XCD.
// ---------------------------------------------------------------------------
__global__ __launch_bounds__(256) void gemm_out(
    const _Float16* __restrict__ A, const _Float16* __restrict__ Wh,
    float* __restrict__ Out, int M)
{
    const int tid = threadIdx.x;
    const int w = tid >> 6, lane = tid & 63;
    const int r = lane & 15, kb = lane >> 4;
    const int lg = xcd_swizzle(blockIdx.x, 58);
    const int l0 = (lg >> 1) * 32;
    const int n0 = (lg & 1) * 256 + w*64;

    const _Float16* ap[2];
    #pragma unroll
    for (int mt = 0; mt < 2; ++mt)
        ap[mt] = A + (size_t)(l0 + mt*16 + r)*512 + kb*8;
    const _Float16* bp[4];
    #pragma unroll
    for (int nt = 0; nt < 4; ++nt)
        bp[nt] = Wh + (size_t)(n0 + nt*16 + r) * 512 + kb*8;

    floatx4 acc[2][4] = {};
    #pragma unroll 2
    for (int k0 = 0; k0 < 512; k0 += 32) {
        half8 a[2], b[4];
        #pragma unroll
        for (int mt = 0; mt < 2; ++mt) a[mt] = *(const half8*)(ap[mt] + k0);
        #pragma unroll
        for (int nt = 0; nt < 4; ++nt) b[nt] = *(const half8*)(bp[nt] + k0);
        #pragma unroll
        for (int mt = 0; mt < 2; ++mt)
            #pragma unroll
            for (int nt = 0; nt < 4; ++nt)
                acc[mt][nt] = MFMA16(a[mt], b[nt], acc[mt][nt]);
    }
    #pragma unroll
    for (int mt = 0; mt < 2; ++mt)
        #pragma unroll
        for (int nt = 0; nt < 4; ++nt)
            #pragma unroll
            for (int i = 0; i < 4; ++i) {
                const int l = l0 + mt*16 + kb*4 + i;
                if (l < M)
                    Out[(size_t)l*512 + n0 + nt*16 + r] = acc[mt][nt][i];
            }
}

// ---------------------------------------------------------------------------
extern "C" void kernel_launch(void* const* d_in, const int* in_sizes, int n_in,
                              void* d_out, int out_size, void* d_ws, size_t ws_size,
                              hipStream_t stream)
{
    (void)in_sizes; (void)n_in; (void)out_size; (void)ws_size;
    const float* static_grid = (const float*)d_in[0];
    const float* history     = (const float*)d_in[1];
    const float* init_embed  = (const float*)d_in[2];
    const float* Wq = (const float*)d_in[3];
    const float* Wk = (const float*)d_in[4];
    const float* Wv = (const float*)d_in[5];
    const float* Wo = (const float*)d_in[6];
    float* out = (float*)d_out;

    char* p = (char*)d_ws;
    _Float16* Wqh  = (_Float16*)p;  p += (size_t)262144 * 2;
    _Float16* Whkv = (_Float16*)p;  p += (size_t)131072 * 2;
    _Float16* Woh  = (_Float16*)p;  p += (size_t)262144 * 2;
    _Float16* Kh   = (_Float16*)p;  p += (size_t)THROWS * 128 * 2;
    _Float16* Vh   = (_Float16*)p;  p += (size_t)THROWS * 128 * 2;
    _Float16* Vt   = (_Float16*)p;  p += (size_t)2 * 64 * VTC * 2;
    _Float16* Qh   = (_Float16*)p;  p += (size_t)928 * 512 * 2;
    _Float16* Oh   = (_Float16*)p;  p += (size_t)928 * 512 * 2;

    // 1) convert weights to fp16
    prep_w<<<320, 256, 0, stream>>>(Wq, Wk, Wv, Wo, Wqh, Whkv, Woh);
    // 2) fused K/V/Q projection + RoPE + V transpose (XCD-swizzled)
    proj<<<1076, 256, 0, stream>>>(init_embed, history, static_grid,
                                   Whkv, Wqh, Kh, Vh, Vt, Qh);
    // 3) masked attention
    attn_f16<<<dim3(57, 8), 256, 0, stream>>>(Qh, Kh, Vt, Vh, Oh);
    // 4) output projection (XCD-swizzled)
    gemm_out<<<58, 256, 0, stream>>>(Oh, Woh, out, S);
}

// Round 11
// 136.574 us; speedup vs baseline: 1.0277x; 1.0277x over previous
//
#include <hip/hip_runtime.h>
#include <math.h>

// Problem constants
static constexpr int GRIDN = 30;
static constexpr int S    = 900;
static constexpr int D    = 512;
static constexpr int HQ   = 8;
static constexpr int HKV  = 2;
static constexpr int T    = 16;
static constexpr int NTOK = 1 + T*S + S;   // 15301
static constexpr int CUR0 = 1 + T*S;       // 14401

static constexpr int THROWS = 15360;       // padded KV rows
static constexpr int VTC    = 960;         // Vt columns
static constexpr int PBS    = 952;         // P LDS row stride (halves)
static constexpr int LSTR   = 72;          // proj LDS row stride (halves, 144B: 16B-aligned rows)

typedef _Float16 half8  __attribute__((ext_vector_type(8)));
typedef _Float16 half4  __attribute__((ext_vector_type(4)));
typedef __fp16   fp16x2 __attribute__((ext_vector_type(2)));
typedef float    floatx4 __attribute__((ext_vector_type(4)));

#define MFMA16(a,b,c) __builtin_amdgcn_mfma_f32_16x16x32_f16((a),(b),(c),0,0,0)

#if defined(__has_builtin)
#if __has_builtin(__builtin_amdgcn_fdot2)
#define HAVE_FDOT2 1
#endif
#endif

__device__ __forceinline__ half8 to_half8(float4 a, float4 b) {
    half8 h;
    h[0]=(_Float16)a.x; h[1]=(_Float16)a.y; h[2]=(_Float16)a.z; h[3]=(_Float16)a.w;
    h[4]=(_Float16)b.x; h[5]=(_Float16)b.y; h[6]=(_Float16)b.z; h[7]=(_Float16)b.w;
    return h;
}

// pack 4 fp32 -> 4 fp16 via v_cvt_pkrtz
__device__ __forceinline__ half4 cvt4(float4 a) {
    const fp16x2 p0 = __builtin_amdgcn_cvt_pkrtz(a.x, a.y);
    const fp16x2 p1 = __builtin_amdgcn_cvt_pkrtz(a.z, a.w);
    half4 h;
    h[0]=(_Float16)p0[0]; h[1]=(_Float16)p0[1];
    h[2]=(_Float16)p1[0]; h[3]=(_Float16)p1[1];
    return h;
}

// ---------------------------------------------------------------------------
// prep_w: weights fp32 -> fp16 only.
// ---------------------------------------------------------------------------
__global__ __launch_bounds__(256) void prep_w(
    const float* __restrict__ Wq, const float* __restrict__ Wk,
    const float* __restrict__ Wv, const float* __restrict__ Wo,
    _Float16* __restrict__ Wqh, _Float16* __restrict__ Whkv,
    _Float16* __restrict__ Woh)
{
    const size_t i8 = ((size_t)blockIdx.x * 256 + threadIdx.x) * 8;
    const float* src; _Float16* dst; size_t off;
    if (i8 < 262144)      { src = Wq; dst = Wqh;          off = i8; }
    else if (i8 < 327680) { src = Wk; dst = Whkv;         off = i8 - 262144; }
    else if (i8 < 393216) { src = Wv; dst = Whkv + 65536; off = i8 - 327680; }
    else                  { src = Wo; dst = Woh;          off = i8 - 393216; }
    const float4 f0 = *(const float4*)(src + off);
    const float4 f1 = *(const float4*)(src + off + 4);
    *(half8*)(dst + off) = to_half8(f0, f1);
}

// ---------------------------------------------------------------------------
// proj: LDS-staged double-buffered GEMM + fused RoPE + V transpose.
// BM=32 x BN=128 x BK=64, 4 waves (2x2).
// Blocks 0..959:    KV (mtile = bx>>1, bc = bx&1: 0=K, 1=V).
// Blocks 960..1075: Q  (qb = bx-960: mtile = qb>>2, bc = qb&3).
// ---------------------------------------------------------------------------
__global__ __launch_bounds__(256) void proj(
    const float* __restrict__ init_e, const float* __restrict__ hist,
    const float* __restrict__ cur,
    const _Float16* __restrict__ Whkv, const _Float16* __restrict__ Wqh,
    _Float16* __restrict__ Kh, _Float16* __restrict__ Vh,
    _Float16* __restrict__ Vt, _Float16* __restrict__ Qh)
{
    __shared__ _Float16 Alds[2][32 * LSTR];    // 9.2 KB
    __shared__ _Float16 Blds[2][128 * LSTR];   // 36.9 KB

    const int tid  = threadIdx.x;
    const int w    = tid >> 6, lane = tid & 63;
    const int r    = lane & 15, kb = lane >> 4;
    const int ww   = w >> 1, wc = w & 1;       // wave row/col in 2x2 grid
    const int bx   = blockIdx.x;
    const bool isQ = (bx >= 960);

    int l0, n0, bc;
    const _Float16* Wb;
    if (!isQ) { l0 = (bx >> 1) * 32;               bc = bx & 1;  n0 = bc * 128; Wb = Whkv; }
    else      { const int qb = bx - 960;
                l0 = CUR0 + (qb >> 2) * 32;        bc = qb & 3;  n0 = bc * 128; Wb = Wqh; }

    // ---- staging source pointers ----
    const float* arow[2];
    #pragma unroll
    for (int j = 0; j < 2; ++j) {
        int l = l0 + j * 16 + (tid >> 4);
        if (l >= NTOK) l = 0;
        const float* rp = (l == 0) ? init_e
                        : (l <= T*S ? hist + (size_t)(l - 1) * 512
                                    : cur  + (size_t)(l - CUR0) * 512);
        arow[j] = rp + (tid & 15) * 4;
    }
    const _Float16* brow[4];
    #pragma unroll
    for (int j = 0; j < 4; ++j)
        brow[j] = Wb + (size_t)(n0 + j * 32 + (tid >> 3)) * 512 + (tid & 7) * 8;

    float4 areg[2];
    half8  breg[4];

    floatx4 acc[4] = {};

    // prologue: chunk 0
    #pragma unroll
    for (int j = 0; j < 2; ++j) areg[j] = *(const float4*)arow[j];
    #pragma unroll
    for (int j = 0; j < 4; ++j) breg[j] = *(const half8*)brow[j];
    #pragma unroll
    for (int j = 0; j < 2; ++j)
        *(half4*)&Alds[0][(j*16 + (tid >> 4)) * LSTR + (tid & 15) * 4] = cvt4(areg[j]);
    #pragma unroll
    for (int j = 0; j < 4; ++j)
        *(half8*)&Blds[0][(j*32 + (tid >> 3)) * LSTR + (tid & 7) * 8]  = breg[j];
    __syncthreads();

    for (int c = 0; c < 8; ++c) {
        const int buf = c & 1;
        if (c < 7) {
            const int k0 = (c + 1) * 64;
            #pragma unroll
            for (int j = 0; j < 2; ++j) areg[j] = *(const float4*)(arow[j] + k0);
            #pragma unroll
            for (int j = 0; j < 4; ++j) breg[j] = *(const half8*)(brow[j] + k0);
        }
        // compute chunk c from LDS[buf]
        #pragma unroll
        for (int s = 0; s < 2; ++s) {
            const half8 a = *(const half8*)&Alds[buf][(ww*16 + r) * LSTR + s*32 + kb*8];
            #pragma unroll
            for (int nt = 0; nt < 4; ++nt) {
                const half8 b = *(const half8*)&Blds[buf][(wc*64 + nt*16 + r) * LSTR + s*32 + kb*8];
                acc[nt] = MFMA16(a, b, acc[nt]);
            }
        }
        if (c < 7) {
            __syncthreads();
            #pragma unroll
            for (int j = 0; j < 2; ++j)
                *(half4*)&Alds[buf ^ 1][(j*16 + (tid >> 4)) * LSTR + (tid & 15) * 4] = cvt4(areg[j]);
            #pragma unroll
            for (int j = 0; j < 4; ++j)
                *(half8*)&Blds[buf ^ 1][(j*32 + (tid >> 3)) * LSTR + (tid & 7) * 8]  = breg[j];
            __syncthreads();
        }
    }

    // ---- epilogue: RoPE + stores ----
    const float LN1E4 = 9.210340371976184f;
    float inv1[4], inv2[4]; int jj[4];
    #pragma unroll
    for (int nt = 0; nt < 4; ++nt) {
        const int cl = nt * 16 + r;          // dim within 64-wide head
        jj[nt] = cl >> 1;
        inv1[nt] = __expf(-(float)jj[nt]        * (LN1E4 / 32.f));
        inv2[nt] = __expf(-(float)(jj[nt] & 15) * (LN1E4 / 16.f));
    }

    if (!isQ) {
        if (bc == 0) {
            // ---- K with rope: col cc = wc*64 + nt*16 + r in [0,128) ----
            #pragma unroll
            for (int i = 0; i < 4; ++i) {
                const int l = l0 + ww*16 + kb*4 + i;
                float pos, cy, cx;
                if (l == 0) { pos = 0.f; cy = 0.f; cx = 0.f; }
                else if (l <= T*S) {
                    const int j2 = l - 1;
                    const int t_ = j2 / S;
                    const int cell = j2 - t_ * S;
                    pos = (float)t_;
                    cy = (float)(cell / GRIDN); cx = (float)(cell % GRIDN);
                } else {
                    const int cell = l - CUR0;
                    pos = (float)T;
                    cy = (float)(cell / GRIDN); cx = (float)(cell % GRIDN);
                }
                #pragma unroll
                for (int nt = 0; nt < 4; ++nt) {
                    const float own = acc[nt][i];
                    const float oth = __shfl_xor(own, 1);
                    const float c2 = (jj[nt] < 16) ? cy : cx;
                    const float theta = pos * inv1[nt] + c2 * inv2[nt];
                    float sn, cs; __sincosf(theta, &sn, &cs);
                    const int cc = wc*64 + nt*16 + r;
                    const float o = ((cc & 1) == 0) ? (own * cs - oth * sn)
                                                    : (oth * sn + own * cs);
                    if (l < NTOK) Kh[(size_t)l * 128 + cc] = (_Float16)o;
                }
            }
        } else {
            // ---- V (no rope): vd = wc*64 + nt*16 + r in [0,128) ----
            #pragma unroll
            for (int nt = 0; nt < 4; ++nt) {
                const int vd = wc*64 + nt*16 + r;
                #pragma unroll
                for (int i = 0; i < 4; ++i) {
                    const int l = l0 + ww*16 + kb*4 + i;
                    if (l >= NTOK) continue;
                    const _Float16 hv = (_Float16)acc[nt][i];
                    Vh[(size_t)l * 128 + vd] = hv;
                    const int cc = l - CUR0;
                    if (cc >= 0 && cc < S)
                        Vt[(size_t)vd * VTC + cc] = hv;   // vd == kvh*64 + d
                }
            }
        }
    } else {
        // ---- Q with rope + 0.125 scale: col C = bc*128 + wc*64 + nt*16 + r ----
        #pragma unroll
        for (int i = 0; i < 4; ++i) {
            const int l = l0 + ww*16 + kb*4 + i;
            const int s = l - CUR0;
            const int ssafe = (s < S) ? s : 0;
            const float cy = (float)(ssafe / GRIDN), cx = (float)(ssafe % GRIDN);
            #pragma unroll
            for (int nt = 0; nt < 4; ++nt) {
                const float own = acc[nt][i];
                const float oth = __shfl_xor(own, 1);
                const float c2 = (jj[nt] < 16) ? cy : cx;
                const float theta = 16.f * inv1[nt] + c2 * inv2[nt];
                float sn, cs; __sincosf(theta, &sn, &cs);
                const int C = bc*128 + wc*64 + nt*16 + r;
                const float o = ((C & 1) == 0) ? (own * cs - oth * sn)
                                               : (oth * sn + own * cs);
                if (s < S)
                    Qh[(size_t)s * 512 + C] = (_Float16)(o * 0.125f);
            }
        }
    }
}

// ---------------------------------------------------------------------------
// Attention: block = (16-query tile, head); 8 waves (512 thr) for TLP.
// Wave w: QK^T tiles nt = w + 8t; PV: d-tile (w&3), key-half (w>>2).
// Dense 900 keys via MFMA, 17 masked extras via dot2 VALU.
// ---------------------------------------------------------------------------
__global__ __launch_bounds__(512) void attn_f16(
    const _Float16* __restrict__ Qh, const _Float16* __restrict__ Kh,
    const _Float16* __restrict__ Vt, const _Float16* __restrict__ Vh,
    _Float16* __restrict__ Oh)
{
    __shared__ _Float16 pb[16][PBS];      // 30.5 KB
    __shared__ float ex[16][20];
    __shared__ float wpm[8][16], wps[8][16];
    __shared__ float rowm[16], rowinv[16];
    __shared__ float Oe[16][68];
    __shared__ float Op[2][16][68];       // PV key-half partials

    const int q0  = blockIdx.x * 16;
    const int h   = blockIdx.y;
    const int kvh = h >> 2;
    const int tid = threadIdx.x;
    const int w = tid >> 6, lane = tid & 63;
    const int r = lane & 15, g = lane >> 4;

    // ---- phase A: extras raw scores (threads with e<17) ----
    {
        const int er = tid & 15;
        const int e  = tid >> 4;     // 0..31
        if (e < 17) {
            const int s  = q0 + er;
            const int ss = (s < S) ? s : 0;
            const _Float16* qp = Qh + (size_t)(q0 + er) * 512 + h * 64;
            const int l = (e == 0) ? 0 : (1 + (e - 1) * S + ss);
            const _Float16* kp = Kh + (size_t)l * 128 + kvh * 64;
            float acc = 0.f;
            #pragma unroll
            for (int d8 = 0; d8 < 8; ++d8) {
                const half8 qv = *(const half8*)(qp + d8 * 8);
                const half8 kv = *(const half8*)(kp + d8 * 8);
#ifdef HAVE_FDOT2
                #pragma unroll
                for (int p_ = 0; p_ < 4; ++p_) {
                    fp16x2 qq; qq[0] = (__fp16)qv[2*p_]; qq[1] = (__fp16)qv[2*p_+1];
                    fp16x2 kk; kk[0] = (__fp16)kv[2*p_]; kk[1] = (__fp16)kv[2*p_+1];
                    acc = __builtin_amdgcn_fdot2(qq, kk, acc, false);
                }
#else
                #pragma unroll
                for (int q_ = 0; q_ < 8; ++q_)
                    acc += (float)qv[q_] * (float)kv[q_];
#endif
            }
            ex[er][e] = acc;
        }
    }

    // ---- phase B: dense QK^T in registers (wave w: tiles w, w+8, ...) ----
    half8 qa[2];
    #pragma unroll
    for (int ks = 0; ks < 2; ++ks)
        qa[ks] = *(const half8*)(Qh + (size_t)(q0 + r) * 512 + h * 64 + ks * 32 + g * 8);

    floatx4 qacc[8];
    #pragma unroll
    for (int t = 0; t < 8; ++t) {
        const int nt = w + 8 * t;
        floatx4 a = {0.f, 0.f, 0.f, 0.f};
        if (nt <= 56) {
            const _Float16* kp = Kh + (size_t)(CUR0 + nt * 16 + r) * 128 + kvh * 64 + g * 8;
            a = MFMA16(qa[0], *(const half8*)kp, a);
            a = MFMA16(qa[1], *(const half8*)(kp + 32), a);
        }
        qacc[t] = a;
    }

    float pm[4] = {-1e30f, -1e30f, -1e30f, -1e30f};
    #pragma unroll
    for (int t = 0; t < 8; ++t) {
        const int nt = w + 8 * t;
        const bool valid = (nt <= 56) && !((nt == 56) && (r >= 4));
        #pragma unroll
        for (int i = 0; i < 4; ++i)
            if (valid) pm[i] = fmaxf(pm[i], qacc[t][i]);
    }
    #pragma unroll
    for (int m = 1; m < 16; m <<= 1)
        #pragma unroll
        for (int i = 0; i < 4; ++i)
            pm[i] = fmaxf(pm[i], __shfl_xor(pm[i], m));
    if (r == 0)
        #pragma unroll
        for (int i = 0; i < 4; ++i) wpm[w][g * 4 + i] = pm[i];
    __syncthreads();

    if (tid < 16) {
        float m = wpm[0][tid];
        #pragma unroll
        for (int w2 = 1; w2 < 8; ++w2) m = fmaxf(m, wpm[w2][tid]);
        #pragma unroll
        for (int e = 0; e < 17; ++e) m = fmaxf(m, ex[tid][e]);
        rowm[tid] = m;
    }
    __syncthreads();

    // ---- phase C: exp + row sums ----
    {
        const int er = tid & 15;
        const int e  = tid >> 4;
        if (e < 17) ex[er][e] = __expf(ex[er][e] - rowm[er]);
    }
    if (tid < 256) pb[tid >> 4][912 + (tid & 15)] = (_Float16)0.f;

    float ps[4] = {0.f, 0.f, 0.f, 0.f};
    #pragma unroll
    for (int t = 0; t < 8; ++t) {
        const int nt = w + 8 * t;
        if (nt <= 56) {
            const int c = nt * 16 + r;
            const bool masked = (nt == 56) && (r >= 4);
            #pragma unroll
            for (int i = 0; i < 4; ++i) {
                const int row = g * 4 + i;
                const float e = masked ? 0.f : __expf(qacc[t][i] - rowm[row]);
                ps[i] += e;
                pb[row][c] = (_Float16)e;
            }
        }
    }
    #pragma unroll
    for (int m = 1; m < 16; m <<= 1)
        #pragma unroll
        for (int i = 0; i < 4; ++i) ps[i] += __shfl_xor(ps[i], m);
    if (r == 0)
        #pragma unroll
        for (int i = 0; i < 4; ++i) wps[w][g * 4 + i] = ps[i];
    __syncthreads();

    if (tid < 16) {
        float s_ = wps[0][tid];
        #pragma unroll
        for (int w2 = 1; w2 < 8; ++w2) s_ += wps[w2][tid];
        #pragma unroll
        for (int e = 0; e < 17; ++e) s_ += ex[tid][e];
        rowinv[tid] = 1.f / s_;
    }
    __syncthreads();

    // ---- phase D: extras PV (fp16 V, fp32 accum; first 256 threads) ----
    if (tid < 256) {
        const int er = tid & 15, gg = tid >> 4;
        const int s  = q0 + er;
        const int ss = (s < S) ? s : 0;
        float o0 = 0.f, o1 = 0.f, o2 = 0.f, o3 = 0.f;
        for (int e = 0; e < 17; ++e) {
            const int l = (e == 0) ? 0 : (1 + (e - 1) * S + ss);
            const float p = ex[er][e];
            const half4 v = *(const half4*)(Vh + (size_t)l * 128 + kvh * 64 + gg * 4);
            o0 = fmaf(p, (float)v[0], o0); o1 = fmaf(p, (float)v[1], o1);
            o2 = fmaf(p, (float)v[2], o2); o3 = fmaf(p, (float)v[3], o3);
        }
        *(float4*)&Oe[er][gg * 4] = make_float4(o0, o1, o2, o3);
    }

    // ---- phase E: dense PV via MFMA (wave w: d-tile w&3, key-half w>>2) ----
    const int d0 = (w & 3) * 16;
    const int kh = w >> 2;
    floatx4 oa = {0.f, 0.f, 0.f, 0.f};
    const _Float16* vrow = Vt + ((size_t)kvh * 64 + d0 + r) * VTC + g * 8;
    const int ks0 = kh ? 15 : 0;
    const int ks1 = kh ? 29 : 15;
    for (int ks = ks0; ks < ks1; ++ks) {
        const half8 pf = *(const half8*)(&pb[r][ks * 32 + g * 8]);
        const half8 vf = *(const half8*)(vrow + ks * 32);
        oa = MFMA16(pf, vf, oa);
    }
    #pragma unroll
    for (int i = 0; i < 4; ++i)
        Op[kh][g * 4 + i][d0 + r] = oa[i];
    __syncthreads();

    if (tid < 256) {
        #pragma unroll
        for (int i = 0; i < 4; ++i) {
            const int row = g * 4 + i;
            const int s = q0 + row;
            if (s < S) {
                const float o = (Op[0][row][w * 16 + r] + Op[1][row][w * 16 + r]
                               + Oe[row][w * 16 + r]) * rowinv[row];
                Oh[(size_t)s * 512 + h * 64 + w * 16 + r] = (_Float16)o;
            }
        }
    }
}

// ---------------------------------------------------------------------------
// Out(fp32)[M][512] = A(fp16, padded rows)[.][512] @ Wh^T.
// ---------------------------------------------------------------------------
__global__ __launch_bounds__(256) void gemm_out(
    const _Float16* __restrict__ A, const _Float16* __restrict__ Wh,
    float* __restrict__ Out, int M)
{
    const int tid = threadIdx.x;
    const int w = tid >> 6, lane = tid & 63;
    const int r = lane & 15, kb = lane >> 4;
    const int l0 = blockIdx.x * 32;
    const int n0 = blockIdx.y * 256 + w*64;

    const _Float16* ap[2];
    #pragma unroll
    for (int mt = 0; mt < 2; ++mt)
        ap[mt] = A + (size_t)(l0 + mt*16 + r)*512 + kb*8;
    const _Float16* bp[4];
    #pragma unroll
    for (int nt = 0; nt < 4; ++nt)
        bp[nt] = Wh + (size_t)(n0 + nt*16 + r) * 512 + kb*8;

    floatx4 acc[2][4] = {};
    #pragma unroll 2
    for (int k0 = 0; k0 < 512; k0 += 32) {
        half8 a[2], b[4];
        #pragma unroll
        for (int mt = 0; mt < 2; ++mt) a[mt] = *(const half8*)(ap[mt] + k0);
        #pragma unroll
        for (int nt = 0; nt < 4; ++nt) b[nt] = *(const half8*)(bp[nt] + k0);
        #pragma unroll
        for (int mt = 0; mt < 2; ++mt)
            #pragma unroll
            for (int nt = 0; nt < 4; ++nt)
                acc[mt][nt] = MFMA16(a[mt], b[nt], acc[mt][nt]);
    }
    #pragma unroll
    for (int mt = 0; mt < 2; ++mt)
        #pragma unroll
        for (int nt = 0; nt < 4; ++nt)
            #pragma unroll
            for (int i = 0; i < 4; ++i) {
                const int l = l0 + mt*16 + kb*4 + i;
                if (l < M)
                    Out[(size_t)l*512 + n0 + nt*16 + r] = acc[mt][nt][i];
            }
}

// ---------------------------------------------------------------------------
extern "C" void kernel_launch(void* const* d_in, const int* in_sizes, int n_in,
                              void* d_out, int out_size, void* d_ws, size_t ws_size,
                              hipStream_t stream)
{
    (void)in_sizes; (void)n_in; (void)out_size; (void)ws_size;
    const float* static_grid = (const float*)d_in[0];
    const float* history     = (const float*)d_in[1];
    const float* init_embed  = (const float*)d_in[2];
    const float* Wq = (const float*)d_in[3];
    const float* Wk = (const float*)d_in[4];
    const float* Wv = (const float*)d_in[5];
    const float* Wo = (const float*)d_in[6];
    float* out = (float*)d_out;

    char* p = (char*)d_ws;
    _Float16* Wqh  = (_Float16*)p;  p += (size_t)262144 * 2;
    _Float16* Whkv = (_Float16*)p;  p += (size_t)131072 * 2;
    _Float16* Woh  = (_Float16*)p;  p += (size_t)262144 * 2;
    _Float16* Kh   = (_Float16*)p;  p += (size_t)THROWS * 128 * 2;
    _Float16* Vh   = (_Float16*)p;  p += (size_t)THROWS * 128 * 2;
    _Float16* Vt   = (_Float16*)p;  p += (size_t)2 * 64 * VTC * 2;
    _Float16* Qh   = (_Float16*)p;  p += (size_t)928 * 512 * 2;
    _Float16* Oh   = (_Float16*)p;  p += (size_t)928 * 512 * 2;

    // 1) convert weights to fp16
    prep_w<<<320, 256, 0, stream>>>(Wq, Wk, Wv, Wo, Wqh, Whkv, Woh);
    // 2) fused K/V/Q projection + RoPE + V transpose
    proj<<<1076, 256, 0, stream>>>(init_embed, history, static_grid,
                                   Whkv, Wqh, Kh, Vh, Vt, Qh);
    // 3) masked attention (8 waves/block)
    attn_f16<<<dim3(57, 8), 512, 0, stream>>>(Qh, Kh, Vt, Vh, Oh);
    // 4) output projection
    gemm_out<<<dim3(29, 2), 256, 0, stream>>>(Oh, Woh, out, S);
}